// Round 12
// baseline (241.790 us; speedup 1.0000x reference)
//
#include <hip/hip_runtime.h>

#define HIDDEN 128
#define NB_SHIFT 7            // 128 dst nodes per bucket
#define NPB 128               // nodes per bucket
#define EPB 4096              // edges per partition/hist block

typedef __attribute__((ext_vector_type(8))) short short8;
typedef __attribute__((ext_vector_type(4))) float f32x4;
typedef _Float16 f16;
typedef __attribute__((ext_vector_type(8))) _Float16 f16x8;

// float -> bf16 (RNE), and back
__device__ __forceinline__ ushort f2bf(float a) {
  union { float f; unsigned u; } c; c.f = a;
  return (ushort)((c.u + 0x7FFFu + ((c.u >> 16) & 1u)) >> 16);
}
__device__ __forceinline__ float bf2f(ushort h) {
  union { unsigned u; float f; } c; c.u = ((unsigned)h) << 16;
  return c.f;
}

// ---------------------------------------------------------------------------
// CSR build A: per-bucket edge histogram (LDS-local, then merge).
// ---------------------------------------------------------------------------
__global__ __launch_bounds__(256) void bucket_hist_kernel(
    const int* __restrict__ dst, int* __restrict__ bcnt, int E, int NB) {
  __shared__ int loc[512];
  const int t = threadIdx.x;
  loc[t] = 0; loc[t + 256] = 0;
  __syncthreads();
  const int base = blockIdx.x * EPB;
  const int end = min(base + EPB, E);
  for (int e = base + t; e < end; e += 256)
    atomicAdd(&loc[dst[e] >> NB_SHIFT], 1);
  __syncthreads();
  for (int b = t; b < NB; b += 256)
    if (loc[b]) atomicAdd(&bcnt[b], loc[b]);
}

// ---------------------------------------------------------------------------
// CSR build B: exclusive scan of <=512 bucket counts -> pairOff + gCursor.
// ---------------------------------------------------------------------------
__global__ __launch_bounds__(256) void scan_buckets_kernel(
    const int* __restrict__ bcnt, int* __restrict__ pairOff,
    int* __restrict__ gCursor, int NB) {
  __shared__ int sh[512];
  const int t = threadIdx.x;
  const int v0 = (t < NB) ? bcnt[t] : 0;
  const int v1 = (t + 256 < NB) ? bcnt[t + 256] : 0;
  sh[t] = v0; sh[t + 256] = v1;
  __syncthreads();
#pragma unroll
  for (int off = 1; off < 512; off <<= 1) {
    int a = (t >= off) ? sh[t - off] : 0;
    int b = (t + 256 >= off) ? sh[t + 256 - off] : 0;
    __syncthreads();
    sh[t] += a; sh[t + 256] += b;
    __syncthreads();
  }
  const int e0 = sh[t] - v0;        // exclusive
  const int e1 = sh[t + 256] - v1;
  pairOff[t] = e0; gCursor[t] = e0;
  pairOff[t + 256] = e1; gCursor[t + 256] = e1;
  if (t == 255) pairOff[512] = sh[511];
}

// ---------------------------------------------------------------------------
// CSR build C: partition edges into bucket-contiguous PACKED pairs:
//   p = (dst & 127) << 25 | src      (src < 2^25)
// ---------------------------------------------------------------------------
__global__ __launch_bounds__(256) void partition_kernel(
    const int* __restrict__ src, const int* __restrict__ dst,
    int* __restrict__ gCursor, int* __restrict__ pairs, int E, int NB) {
  __shared__ int loc[512];
  __shared__ int cur[512];
  const int t = threadIdx.x;
  loc[t] = 0; loc[t + 256] = 0;
  __syncthreads();
  const int base = blockIdx.x * EPB;
  const int end = min(base + EPB, E);
  for (int e = base + t; e < end; e += 256)
    atomicAdd(&loc[dst[e] >> NB_SHIFT], 1);
  __syncthreads();
  for (int b = t; b < NB; b += 256)
    cur[b] = loc[b] ? atomicAdd(&gCursor[b], loc[b]) : 0;
  __syncthreads();
  for (int e = base + t; e < end; e += 256) {
    const int d = dst[e];
    const int p = atomicAdd(&cur[d >> NB_SHIFT], 1);
    pairs[p] = ((d & (NPB - 1)) << 25) | src[e];
  }
}

// ---------------------------------------------------------------------------
// CSR build D: one block per bucket -> rowptr + col (dense, L2-resident).
// ---------------------------------------------------------------------------
__global__ __launch_bounds__(256) void build_csr_kernel(
    const int* __restrict__ pairs, const int* __restrict__ pairOff,
    int* __restrict__ rowptr, int* __restrict__ col, int M, int E, int NB) {
  __shared__ int deg[NPB];
  __shared__ int pre[NPB];
  __shared__ int cur[NPB];
  const int b = blockIdx.x;
  const int t = threadIdx.x;
  const int s = pairOff[b];
  const int e2 = pairOff[b + 1];
  const int nodeBase = b << NB_SHIFT;
  const int nNodes = min(NPB, M - nodeBase);
  if (t < NPB) deg[t] = 0;
  __syncthreads();
  for (int i = s + t; i < e2; i += 256)
    atomicAdd(&deg[((unsigned)pairs[i]) >> 25], 1);
  __syncthreads();
  if (t < NPB) pre[t] = deg[t];
  __syncthreads();
#pragma unroll
  for (int off = 1; off < NPB; off <<= 1) {
    int v = (t < NPB && t >= off) ? pre[t - off] : 0;
    __syncthreads();
    if (t < NPB) pre[t] += v;
    __syncthreads();
  }
  if (t < nNodes) rowptr[nodeBase + t] = s + pre[t] - deg[t];
  if (b == NB - 1 && t == 0) rowptr[M] = E;
  if (t < NPB) cur[t] = pre[t] - deg[t];
  __syncthreads();
  for (int i = s + t; i < e2; i += 256) {
    const int pr = pairs[i];
    const int pos = s + atomicAdd(&cur[((unsigned)pr) >> 25], 1);
    col[pos] = pr & 0x1FFFFFF;
  }
}

// ---------------------------------------------------------------------------
// fp32 -> fp16 feature convert (8 elems/thread)
// ---------------------------------------------------------------------------
__global__ __launch_bounds__(256) void f2h_kernel(const float* __restrict__ in,
                                                  f16* __restrict__ out, int n8) {
  int i = blockIdx.x * 256 + threadIdx.x;
  if (i >= n8) return;
  const float4* p = (const float4*)(in + (size_t)i * 8);
  float4 a = p[0], b = p[1];
  f16x8 o;
  o[0] = (f16)a.x; o[1] = (f16)a.y; o[2] = (f16)a.z; o[3] = (f16)a.w;
  o[4] = (f16)b.x; o[5] = (f16)b.y; o[6] = (f16)b.z; o[7] = (f16)b.w;
  *(f16x8*)(out + (size_t)i * 8) = o;
}

// ---------------------------------------------------------------------------
// Prepack weights into MFMA B-fragment-linear bf16 hi/lo planes.
//   frag (ks, nf), lane, j  ->  k = ks*32 + (lane>>4)*8 + j, n = nf*16 + (lane&15)
// ---------------------------------------------------------------------------
__global__ __launch_bounds__(256) void prepack_kernel(
    const float* __restrict__ Wa, const float* __restrict__ Wb,
    const float* __restrict__ Wc, const float* __restrict__ Wd,
    ushort* __restrict__ out) {
  int idx = blockIdx.x * 256 + threadIdx.x;  // 0..8191
  int w = idx >> 11;
  int rem = idx & 2047;
  int ks = rem >> 9;
  int nf = (rem >> 6) & 7;
  int lane = rem & 63;
  const float* W = (w == 0) ? Wa : (w == 1) ? Wb : (w == 2) ? Wc : Wd;
  const int kbase = ks * 32 + (lane >> 4) * 8;
  const int n = nf * 16 + (lane & 15);
  ushort* oh = out + (size_t)w * 32768 + (size_t)rem * 8;
  ushort* ol = oh + 16384;
#pragma unroll
  for (int j = 0; j < 8; ++j) {
    float v = W[(size_t)(kbase + j) * HIDDEN + n];
    ushort h = f2bf(v);
    oh[j] = h;
    ol[j] = f2bf(v - bf2f(h));
  }
}

// ---------------------------------------------------------------------------
// FUSED GIN layer, 4-WAY edge-split. Block = 256 threads = 4 waves per
// 16-node group. R11 (2-way split) confirmed concurrency is the lever
// (+15%, the only positive response across R7-R11). Here wave w gathers
// edge quarter [s+len*w/4, s+len*(w+1)/4) of the SAME 16 nodes -> 12500
// waves supplied (~49/CU; residency ~16/CU with a block queue smoothing
// the drain tail vs R11's all-resident-then-drain).
// Deterministic combine tree via two LDS buffers: full = (w0+w1)+(w2+w3).
// MLP splits 2 nf fragments per wave (total MFMA unchanged). VGPR budget
// generous (launch_bounds(256,4) = 128 cap) per R10's spill lesson.
// LDS 17.1 KB.
// ---------------------------------------------------------------------------
__global__ __launch_bounds__(256, 4) void gin_layer_kernel(
    const f16* __restrict__ xh, const int* __restrict__ rowptr,
    const int* __restrict__ col, const ushort* __restrict__ W1p,
    const float* __restrict__ b1, const ushort* __restrict__ W2p,
    const float* __restrict__ b2, f16* __restrict__ Ch,
    const float* __restrict__ Wr, const float* __restrict__ br,
    float* __restrict__ outv, int M, int doReadout) {
  __shared__ float bufA[16][132];
  __shared__ float bufB[16][132];
  __shared__ float pr[3][16];
  const int t = threadIdx.x;
  const int lane = t & 63;
  const int w = t >> 6;        // wave quarter: 0..3
  const int r = lane & 15;     // node row within group / D col index
  const int g = lane >> 4;     // k-group / D row group
  const int mBase = blockIdx.x * 16;
  int arow = mBase + r;
  if (arow > M - 1) arow = M - 1;  // clamp: garbage only affects rows >= M

  // ---- gather partial over this wave's edge quarter (+ self on wave 0)
  float a32[4][8];
  if (w == 0) {
    const f16* rp = xh + (size_t)arow * HIDDEN + g * 8;
    f16x8 s0 = *(const f16x8*)(rp);
    f16x8 s1 = *(const f16x8*)(rp + 32);
    f16x8 s2 = *(const f16x8*)(rp + 64);
    f16x8 s3 = *(const f16x8*)(rp + 96);
#pragma unroll
    for (int j = 0; j < 8; ++j) {
      a32[0][j] = (float)s0[j]; a32[1][j] = (float)s1[j];
      a32[2][j] = (float)s2[j]; a32[3][j] = (float)s3[j];
    }
  } else {
#pragma unroll
    for (int ks = 0; ks < 4; ++ks)
#pragma unroll
      for (int j = 0; j < 8; ++j) a32[ks][j] = 0.f;
  }
  {
    const int sAll = rowptr[arow];
    const int len = rowptr[arow + 1] - sAll;
    const int s = sAll + ((len * w) >> 2);
    const int e = sAll + ((len * (w + 1)) >> 2);
    int i = s;
    // 2-edge unroll (8 f16x8 temps = 32 VGPR; no spill at 128 budget)
    for (; i + 1 < e; i += 2) {
      const int c0 = col[i], c1 = col[i + 1];
      const f16* p0 = xh + (size_t)c0 * HIDDEN + g * 8;
      const f16* p1 = xh + (size_t)c1 * HIDDEN + g * 8;
      f16x8 u0 = *(const f16x8*)(p0);
      f16x8 u1 = *(const f16x8*)(p0 + 32);
      f16x8 u2 = *(const f16x8*)(p0 + 64);
      f16x8 u3 = *(const f16x8*)(p0 + 96);
      f16x8 v0 = *(const f16x8*)(p1);
      f16x8 v1 = *(const f16x8*)(p1 + 32);
      f16x8 v2 = *(const f16x8*)(p1 + 64);
      f16x8 v3 = *(const f16x8*)(p1 + 96);
#pragma unroll
      for (int j = 0; j < 8; ++j) {
        a32[0][j] += (float)u0[j] + (float)v0[j];
        a32[1][j] += (float)u1[j] + (float)v1[j];
        a32[2][j] += (float)u2[j] + (float)v2[j];
        a32[3][j] += (float)u3[j] + (float)v3[j];
      }
    }
    if (i < e) {
      const int c0 = col[i];
      const f16* p0 = xh + (size_t)c0 * HIDDEN + g * 8;
      f16x8 u0 = *(const f16x8*)(p0);
      f16x8 u1 = *(const f16x8*)(p0 + 32);
      f16x8 u2 = *(const f16x8*)(p0 + 64);
      f16x8 u3 = *(const f16x8*)(p0 + 96);
#pragma unroll
      for (int j = 0; j < 8; ++j) {
        a32[0][j] += (float)u0[j];
        a32[1][j] += (float)u1[j];
        a32[2][j] += (float)u2[j];
        a32[3][j] += (float)u3[j];
      }
    }
  }

  // ---- deterministic combine: full = (w0+w1) + (w2+w3)
  if (w == 1 || w == 3) {
    float (*dstb)[132] = (w == 1) ? bufA : bufB;
#pragma unroll
    for (int ks = 0; ks < 4; ++ks) {
      *(float4*)&dstb[r][ks * 32 + g * 8] =
          make_float4(a32[ks][0], a32[ks][1], a32[ks][2], a32[ks][3]);
      *(float4*)&dstb[r][ks * 32 + g * 8 + 4] =
          make_float4(a32[ks][4], a32[ks][5], a32[ks][6], a32[ks][7]);
    }
  }
  __syncthreads();
  if (w == 0 || w == 2) {
    float (*srcb)[132] = (w == 0) ? bufA : bufB;
#pragma unroll
    for (int ks = 0; ks < 4; ++ks) {
      float4 q0 = *(const float4*)&srcb[r][ks * 32 + g * 8];
      float4 q1 = *(const float4*)&srcb[r][ks * 32 + g * 8 + 4];
      a32[ks][0] += q0.x; a32[ks][1] += q0.y; a32[ks][2] += q0.z; a32[ks][3] += q0.w;
      a32[ks][4] += q1.x; a32[ks][5] += q1.y; a32[ks][6] += q1.z; a32[ks][7] += q1.w;
    }
  }
  __syncthreads();
  if (w == 2) {  // (w2+w3) -> bufA
#pragma unroll
    for (int ks = 0; ks < 4; ++ks) {
      *(float4*)&bufA[r][ks * 32 + g * 8] =
          make_float4(a32[ks][0], a32[ks][1], a32[ks][2], a32[ks][3]);
      *(float4*)&bufA[r][ks * 32 + g * 8 + 4] =
          make_float4(a32[ks][4], a32[ks][5], a32[ks][6], a32[ks][7]);
    }
  }
  __syncthreads();
  if (w == 0) {  // full sum -> bufB
#pragma unroll
    for (int ks = 0; ks < 4; ++ks) {
      float4 q0 = *(const float4*)&bufA[r][ks * 32 + g * 8];
      float4 q1 = *(const float4*)&bufA[r][ks * 32 + g * 8 + 4];
      a32[ks][0] += q0.x; a32[ks][1] += q0.y; a32[ks][2] += q0.z; a32[ks][3] += q0.w;
      a32[ks][4] += q1.x; a32[ks][5] += q1.y; a32[ks][6] += q1.z; a32[ks][7] += q1.w;
      *(float4*)&bufB[r][ks * 32 + g * 8] =
          make_float4(a32[ks][0], a32[ks][1], a32[ks][2], a32[ks][3]);
      *(float4*)&bufB[r][ks * 32 + g * 8 + 4] =
          make_float4(a32[ks][4], a32[ks][5], a32[ks][6], a32[ks][7]);
    }
  }
  __syncthreads();
  if (w != 0) {  // waves 1-3 load full sum
#pragma unroll
    for (int ks = 0; ks < 4; ++ks) {
      float4 q0 = *(const float4*)&bufB[r][ks * 32 + g * 8];
      float4 q1 = *(const float4*)&bufB[r][ks * 32 + g * 8 + 4];
      a32[ks][0] = q0.x; a32[ks][1] = q0.y; a32[ks][2] = q0.z; a32[ks][3] = q0.w;
      a32[ks][4] = q1.x; a32[ks][5] = q1.y; a32[ks][6] = q1.z; a32[ks][7] = q1.w;
    }
  }

  f32x4 acc[2];      // this wave's 2 nf fragments: nf = w*2 + nfi
#pragma unroll
  for (int i = 0; i < 2; ++i) acc[i] = (f32x4){0.f, 0.f, 0.f, 0.f};

  // ---- GEMM1: acc[nfi] += a32(16x128) @ W1[:, (w*2+nfi)*16..]
#pragma unroll
  for (int ks = 0; ks < 4; ++ks) {
    short8 ah, al;
#pragma unroll
    for (int j = 0; j < 8; ++j) {
      ushort hh = f2bf(a32[ks][j]);
      ah[j] = (short)hh;
      al[j] = (short)f2bf(a32[ks][j] - bf2f(hh));
    }
#pragma unroll
    for (int nfi = 0; nfi < 2; ++nfi) {
      const ushort* bp = W1p + ((size_t)(ks * 8 + w * 2 + nfi) * 64 + lane) * 8;
      short8 bh = *(const short8*)bp;
      short8 bl = *(const short8*)(bp + 16384);
      acc[nfi] = __builtin_amdgcn_mfma_f32_16x16x32_bf16(ah, bh, acc[nfi], 0, 0, 0);
      acc[nfi] = __builtin_amdgcn_mfma_f32_16x16x32_bf16(al, bh, acc[nfi], 0, 0, 0);
      acc[nfi] = __builtin_amdgcn_mfma_f32_16x16x32_bf16(ah, bl, acc[nfi], 0, 0, 0);
    }
  }
  __syncthreads();   // bufB (a32 source) reads done before h1 overwrite? h1 -> bufA; bufA free after w0's read. This barrier orders w1-3's bufB reads before epilogue reuse of bufB.

  // ---- bias + relu -> h1 (cols [w*32, w*32+32)) in bufA
#pragma unroll
  for (int nfi = 0; nfi < 2; ++nfi) {
    const int nf = w * 2 + nfi;
    float bv = b1[nf * 16 + r];
#pragma unroll
    for (int q = 0; q < 4; ++q)
      bufA[g * 4 + q][nf * 16 + r] = fmaxf(acc[nfi][q] + bv, 0.f);
    acc[nfi] = (f32x4){0.f, 0.f, 0.f, 0.f};
  }
  __syncthreads();   // full h1 visible

  // ---- GEMM2: acc[nfi] += h1(16x128) @ W2[:, (w*2+nfi)*16..]
#pragma unroll
  for (int ks = 0; ks < 4; ++ks) {
    const float* hp = &bufA[r][ks * 32 + g * 8];
    float4 a0 = *(const float4*)hp;
    float4 a1 = *(const float4*)(hp + 4);
    float av[8] = {a0.x, a0.y, a0.z, a0.w, a1.x, a1.y, a1.z, a1.w};
    short8 ah, al;
#pragma unroll
    for (int j = 0; j < 8; ++j) {
      ushort hh = f2bf(av[j]);
      ah[j] = (short)hh;
      al[j] = (short)f2bf(av[j] - bf2f(hh));
    }
#pragma unroll
    for (int nfi = 0; nfi < 2; ++nfi) {
      const ushort* bp = W2p + ((size_t)(ks * 8 + w * 2 + nfi) * 64 + lane) * 8;
      short8 bh = *(const short8*)bp;
      short8 bl = *(const short8*)(bp + 16384);
      acc[nfi] = __builtin_amdgcn_mfma_f32_16x16x32_bf16(ah, bh, acc[nfi], 0, 0, 0);
      acc[nfi] = __builtin_amdgcn_mfma_f32_16x16x32_bf16(al, bh, acc[nfi], 0, 0, 0);
      acc[nfi] = __builtin_amdgcn_mfma_f32_16x16x32_bf16(ah, bl, acc[nfi], 0, 0, 0);
    }
  }

  if (!doReadout) {
    // h2 -> bufB (no clash with bufA reads), then coalesced fp16 stores
#pragma unroll
    for (int nfi = 0; nfi < 2; ++nfi) {
      const int nf = w * 2 + nfi;
      float bv = b2[nf * 16 + r];
#pragma unroll
      for (int q = 0; q < 4; ++q)
        bufB[g * 4 + q][nf * 16 + r] = fmaxf(acc[nfi][q] + bv, 0.f);
    }
    __syncthreads();
    // 256 threads cover 16 rows x 128 cols: one f16x8 per thread
    const int rr = t >> 4;             // 0..15
    const int c0 = (t & 15) * 8;       // 0..120
    const int gm = mBase + rr;
    if (gm < M) {
      float4 v0 = *(const float4*)&bufB[rr][c0];
      float4 v1 = *(const float4*)&bufB[rr][c0 + 4];
      f16x8 o;
      o[0] = (f16)v0.x; o[1] = (f16)v0.y; o[2] = (f16)v0.z; o[3] = (f16)v0.w;
      o[4] = (f16)v1.x; o[5] = (f16)v1.y; o[6] = (f16)v1.z; o[7] = (f16)v1.w;
      *(f16x8*)(Ch + (size_t)gm * HIDDEN + c0) = o;
    }
  } else {
    // readout: each wave dots its 32 cols, reduce over r-lanes, combine 4
    // wave partials via pr[3][16].
    float p[4] = {0.f, 0.f, 0.f, 0.f};
#pragma unroll
    for (int nfi = 0; nfi < 2; ++nfi) {
      const int nf = w * 2 + nfi;
      float bv = b2[nf * 16 + r];
      float wv = Wr[nf * 16 + r];
#pragma unroll
      for (int q = 0; q < 4; ++q) {
        float hv = fmaxf(acc[nfi][q] + bv, 0.f);
        p[q] += hv * wv;
      }
    }
#pragma unroll
    for (int q = 0; q < 4; ++q) {
      p[q] += __shfl_xor(p[q], 8);
      p[q] += __shfl_xor(p[q], 4);
      p[q] += __shfl_xor(p[q], 2);
      p[q] += __shfl_xor(p[q], 1);
    }
    if (w != 0 && r == 0) {
#pragma unroll
      for (int q = 0; q < 4; ++q) pr[w - 1][g * 4 + q] = p[q];
    }
    __syncthreads();
    if (w == 0 && r == 0) {
      float brv = br[0];
#pragma unroll
      for (int q = 0; q < 4; ++q) {
        int gm = mBase + g * 4 + q;
        if (gm < M)
          outv[gm] = p[q] + pr[0][g * 4 + q] + pr[1][g * 4 + q] +
                     pr[2][g * 4 + q] + brv;
      }
    }
  }
}

extern "C" void kernel_launch(void* const* d_in, const int* in_sizes, int n_in,
                              void* d_out, int out_size, void* d_ws,
                              size_t ws_size, hipStream_t stream) {
  const float* x = (const float*)d_in[0];
  const int* ei = (const int*)d_in[1];
  const float* W1_0 = (const float*)d_in[2];
  const float* b1_0 = (const float*)d_in[3];
  const float* W2_0 = (const float*)d_in[4];
  const float* b2_0 = (const float*)d_in[5];
  const float* W1_1 = (const float*)d_in[6];
  const float* b1_1 = (const float*)d_in[7];
  const float* W2_1 = (const float*)d_in[8];
  const float* b2_1 = (const float*)d_in[9];
  const float* Wr = (const float*)d_in[10];
  const float* br = (const float*)d_in[11];

  const int M = in_sizes[0] / HIDDEN;  // 50000 nodes
  const int E = in_sizes[1] / 2;       // 800000 edges
  const int* src = ei;
  const int* dst = ei + E;
  const int NB = (M + NPB - 1) >> NB_SHIFT;  // 391 buckets

  // workspace layout. pairs dies after build_csr; scratch region reused.
  int* pairs = (int*)d_ws;                   // [E] packed (dst&127)<<25|src
  f16* xh = (f16*)(pairs + E);               // [M,128] fp16 features
  f16* Bh = xh + (size_t)M * HIDDEN;         // [M,128] fp16 layer-0 hidden
  int* rowptr = (int*)(Bh + (size_t)M * HIDDEN); // [M+1]
  int* col = rowptr + M + 1;                 // [E]
  int* bcnt = col + E;                       // [512]
  int* pairOff = bcnt + 512;                 // [513]
  int* gCursor = pairOff + 513;              // [512]
  ushort* Wpk = (ushort*)(gCursor + 512);    // 4 x (hi 32KB + lo 32KB)

  const int ginBlocks = (M + 15) / 16;       // 1 block = 4 waves = 16 nodes
  const int cvtBlocks = (M * 16 + 255) / 256;  // M*128/8 threads
  const int edgeBlocks = (E + EPB - 1) / EPB;
  float* out = (float*)d_out;

  // ---- prepack weights + fp16 feature copy (independent of CSR chain)
  prepack_kernel<<<32, 256, 0, stream>>>(W1_0, W2_0, W1_1, W2_1, Wpk);
  f2h_kernel<<<cvtBlocks, 256, 0, stream>>>(x, xh, M * 16);

  // ---- build CSR via bucket sort
  hipMemsetAsync(bcnt, 0, 512 * sizeof(int), stream);
  bucket_hist_kernel<<<edgeBlocks, 256, 0, stream>>>(dst, bcnt, E, NB);
  scan_buckets_kernel<<<1, 256, 0, stream>>>(bcnt, pairOff, gCursor, NB);
  partition_kernel<<<edgeBlocks, 256, 0, stream>>>(src, dst, gCursor, pairs,
                                                   E, NB);
  build_csr_kernel<<<NB, 256, 0, stream>>>(pairs, pairOff, rowptr, col, M, E,
                                           NB);

  // ---- layer 0: fused gather+MLP (xh -> Bh fp16)
  gin_layer_kernel<<<ginBlocks, 256, 0, stream>>>(
      xh, rowptr, col, Wpk, b1_0, Wpk + 32768, b2_0, Bh,
      nullptr, nullptr, nullptr, M, 0);

  // ---- layer 1: fused gather+MLP+readout (Bh -> out)
  gin_layer_kernel<<<ginBlocks, 256, 0, stream>>>(
      Bh, rowptr, col, Wpk + 65536, b1_1, Wpk + 98304, b2_1, nullptr,
      Wr, br, out, M, 1);
}

// Round 13
// 239.633 us; speedup vs baseline: 1.0090x; 1.0090x over previous
//
#include <hip/hip_runtime.h>

#define HIDDEN 128
#define NB_SHIFT 7            // 128 dst nodes per bucket
#define NPB 128               // nodes per bucket
#define EPB 4096              // edges per partition/hist block

typedef __attribute__((ext_vector_type(8))) short short8;
typedef __attribute__((ext_vector_type(4))) float f32x4;
typedef _Float16 f16;
typedef __attribute__((ext_vector_type(8))) _Float16 f16x8;

// float -> bf16 (RNE), and back
__device__ __forceinline__ ushort f2bf(float a) {
  union { float f; unsigned u; } c; c.f = a;
  return (ushort)((c.u + 0x7FFFu + ((c.u >> 16) & 1u)) >> 16);
}
__device__ __forceinline__ float bf2f(ushort h) {
  union { unsigned u; float f; } c; c.u = ((unsigned)h) << 16;
  return c.f;
}

// ---------------------------------------------------------------------------
// PREP kernel: prepack weights (blocks 0..31) + fp32->fp16 convert (blocks
// 32..) + bcnt zeroing (block 0). Merges 3 dispatches into 1 (launch-
// overhead shave; all three are independent of the CSR chain).
// Prepack fragment mapping (must match mlp A-side):
//   frag (ks, nf), lane, j -> k = ks*32 + (lane>>4)*8 + j, n = nf*16 + (lane&15)
// ---------------------------------------------------------------------------
__global__ __launch_bounds__(256) void prep_kernel(
    const float* __restrict__ Wa, const float* __restrict__ Wb,
    const float* __restrict__ Wc, const float* __restrict__ Wd,
    ushort* __restrict__ wout, const float* __restrict__ xin,
    f16* __restrict__ xh, int n8, int* __restrict__ bcnt) {
  const int t = threadIdx.x;
  if (blockIdx.x < 32) {
    if (blockIdx.x == 0) { bcnt[t] = 0; bcnt[t + 256] = 0; }
    int idx = blockIdx.x * 256 + t;  // 0..8191
    int w = idx >> 11;
    int rem = idx & 2047;
    int ks = rem >> 9;
    int nf = (rem >> 6) & 7;
    int lane = rem & 63;
    const float* W = (w == 0) ? Wa : (w == 1) ? Wb : (w == 2) ? Wc : Wd;
    const int kbase = ks * 32 + (lane >> 4) * 8;
    const int n = nf * 16 + (lane & 15);
    ushort* oh = wout + (size_t)w * 32768 + (size_t)rem * 8;
    ushort* ol = oh + 16384;
#pragma unroll
    for (int j = 0; j < 8; ++j) {
      float v = W[(size_t)(kbase + j) * HIDDEN + n];
      ushort h = f2bf(v);
      oh[j] = h;
      ol[j] = f2bf(v - bf2f(h));
    }
  } else {
    int i = (blockIdx.x - 32) * 256 + t;
    if (i >= n8) return;
    const float4* p = (const float4*)(xin + (size_t)i * 8);
    float4 a = p[0], b = p[1];
    f16x8 o;
    o[0] = (f16)a.x; o[1] = (f16)a.y; o[2] = (f16)a.z; o[3] = (f16)a.w;
    o[4] = (f16)b.x; o[5] = (f16)b.y; o[6] = (f16)b.z; o[7] = (f16)b.w;
    *(f16x8*)(xh + (size_t)i * 8) = o;
  }
}

// ---------------------------------------------------------------------------
// CSR build A: per-bucket edge histogram (LDS-local, then merge).
// ---------------------------------------------------------------------------
__global__ __launch_bounds__(256) void bucket_hist_kernel(
    const int* __restrict__ dst, int* __restrict__ bcnt, int E, int NB) {
  __shared__ int loc[512];
  const int t = threadIdx.x;
  loc[t] = 0; loc[t + 256] = 0;
  __syncthreads();
  const int base = blockIdx.x * EPB;
  const int end = min(base + EPB, E);
  for (int e = base + t; e < end; e += 256)
    atomicAdd(&loc[dst[e] >> NB_SHIFT], 1);
  __syncthreads();
  for (int b = t; b < NB; b += 256)
    if (loc[b]) atomicAdd(&bcnt[b], loc[b]);
}

// ---------------------------------------------------------------------------
// CSR build B: exclusive scan of <=512 bucket counts -> pairOff + gCursor.
// ---------------------------------------------------------------------------
__global__ __launch_bounds__(256) void scan_buckets_kernel(
    const int* __restrict__ bcnt, int* __restrict__ pairOff,
    int* __restrict__ gCursor, int NB) {
  __shared__ int sh[512];
  const int t = threadIdx.x;
  const int v0 = (t < NB) ? bcnt[t] : 0;
  const int v1 = (t + 256 < NB) ? bcnt[t + 256] : 0;
  sh[t] = v0; sh[t + 256] = v1;
  __syncthreads();
#pragma unroll
  for (int off = 1; off < 512; off <<= 1) {
    int a = (t >= off) ? sh[t - off] : 0;
    int b = (t + 256 >= off) ? sh[t + 256 - off] : 0;
    __syncthreads();
    sh[t] += a; sh[t + 256] += b;
    __syncthreads();
  }
  const int e0 = sh[t] - v0;        // exclusive
  const int e1 = sh[t + 256] - v1;
  pairOff[t] = e0; gCursor[t] = e0;
  pairOff[t + 256] = e1; gCursor[t + 256] = e1;
  if (t == 255) pairOff[512] = sh[511];
}

// ---------------------------------------------------------------------------
// CSR build C: partition edges into bucket-contiguous PACKED pairs:
//   p = (dst & 127) << 25 | src      (src < 2^25)
// ---------------------------------------------------------------------------
__global__ __launch_bounds__(256) void partition_kernel(
    const int* __restrict__ src, const int* __restrict__ dst,
    int* __restrict__ gCursor, int* __restrict__ pairs, int E, int NB) {
  __shared__ int loc[512];
  __shared__ int cur[512];
  const int t = threadIdx.x;
  loc[t] = 0; loc[t + 256] = 0;
  __syncthreads();
  const int base = blockIdx.x * EPB;
  const int end = min(base + EPB, E);
  for (int e = base + t; e < end; e += 256)
    atomicAdd(&loc[dst[e] >> NB_SHIFT], 1);
  __syncthreads();
  for (int b = t; b < NB; b += 256)
    cur[b] = loc[b] ? atomicAdd(&gCursor[b], loc[b]) : 0;
  __syncthreads();
  for (int e = base + t; e < end; e += 256) {
    const int d = dst[e];
    const int p = atomicAdd(&cur[d >> NB_SHIFT], 1);
    pairs[p] = ((d & (NPB - 1)) << 25) | src[e];
  }
}

// ---------------------------------------------------------------------------
// CSR build D: one block per bucket -> rowptr + col (dense, L2-resident).
// ---------------------------------------------------------------------------
__global__ __launch_bounds__(256) void build_csr_kernel(
    const int* __restrict__ pairs, const int* __restrict__ pairOff,
    int* __restrict__ rowptr, int* __restrict__ col, int M, int E, int NB) {
  __shared__ int deg[NPB];
  __shared__ int pre[NPB];
  __shared__ int cur[NPB];
  const int b = blockIdx.x;
  const int t = threadIdx.x;
  const int s = pairOff[b];
  const int e2 = pairOff[b + 1];
  const int nodeBase = b << NB_SHIFT;
  const int nNodes = min(NPB, M - nodeBase);
  if (t < NPB) deg[t] = 0;
  __syncthreads();
  for (int i = s + t; i < e2; i += 256)
    atomicAdd(&deg[((unsigned)pairs[i]) >> 25], 1);
  __syncthreads();
  if (t < NPB) pre[t] = deg[t];
  __syncthreads();
#pragma unroll
  for (int off = 1; off < NPB; off <<= 1) {
    int v = (t < NPB && t >= off) ? pre[t - off] : 0;
    __syncthreads();
    if (t < NPB) pre[t] += v;
    __syncthreads();
  }
  if (t < nNodes) rowptr[nodeBase + t] = s + pre[t] - deg[t];
  if (b == NB - 1 && t == 0) rowptr[M] = E;
  if (t < NPB) cur[t] = pre[t] - deg[t];
  __syncthreads();
  for (int i = s + t; i < e2; i += 256) {
    const int pr = pairs[i];
    const int pos = s + atomicAdd(&cur[((unsigned)pr) >> 25], 1);
    col[pos] = pr & 0x1FFFFFF;
  }
}

// ---------------------------------------------------------------------------
// FUSED GIN layer, EDGE-SPLIT wave pairs (R11 structure, symmetric combine).
// Block = 128 threads = 2 waves per 16-node group; wave h gathers edge half
// [s,mid)/[mid,e) of the SAME 16 nodes (6250 waves, the R11 concurrency
// win). COMBINE (new): both waves write partials to separate LDS buffers,
// ONE barrier, each wave reads the OTHER buffer and adds locally (IEEE add
// is commutative -> both get bit-identical sums). 6 barriers -> 4, no
// idle-wave phases (R11's 4-phase alternating combine had one wave idle per
// phase; R12's 4-way tree regressed on exactly this overhead).
// MLP splits nf 0-3 / 4-7 per wave. launch_bounds(128,4) = 128-VGPR budget
// (R10 spill lesson). LDS 17 KB.
// ---------------------------------------------------------------------------
__global__ __launch_bounds__(128, 4) void gin_layer_kernel(
    const f16* __restrict__ xh, const int* __restrict__ rowptr,
    const int* __restrict__ col, const ushort* __restrict__ W1p,
    const float* __restrict__ b1, const ushort* __restrict__ W2p,
    const float* __restrict__ b2, f16* __restrict__ Ch,
    const float* __restrict__ Wr, const float* __restrict__ br,
    float* __restrict__ outv, int M, int doReadout) {
  __shared__ float bufA[16][132];
  __shared__ float bufB[16][132];
  __shared__ float pr[16];
  const int t = threadIdx.x;
  const int lane = t & 63;
  const int h = t >> 6;        // wave half: 0 or 1
  const int r = lane & 15;     // node row within group / D col index
  const int g = lane >> 4;     // k-group / D row group
  const int mBase = blockIdx.x * 16;
  int arow = mBase + r;
  if (arow > M - 1) arow = M - 1;  // clamp: garbage only affects rows >= M

  // ---- gather partial over this wave's edge half (+ self term on wave 0)
  float a32[4][8];
  if (h == 0) {
    const f16* rp = xh + (size_t)arow * HIDDEN + g * 8;
    f16x8 s0 = *(const f16x8*)(rp);
    f16x8 s1 = *(const f16x8*)(rp + 32);
    f16x8 s2 = *(const f16x8*)(rp + 64);
    f16x8 s3 = *(const f16x8*)(rp + 96);
#pragma unroll
    for (int j = 0; j < 8; ++j) {
      a32[0][j] = (float)s0[j]; a32[1][j] = (float)s1[j];
      a32[2][j] = (float)s2[j]; a32[3][j] = (float)s3[j];
    }
  } else {
#pragma unroll
    for (int ks = 0; ks < 4; ++ks)
#pragma unroll
      for (int j = 0; j < 8; ++j) a32[ks][j] = 0.f;
  }
  {
    const int sAll = rowptr[arow];
    const int eAll = rowptr[arow + 1];
    const int mid = sAll + ((eAll - sAll) >> 1);
    const int s = h ? mid : sAll;
    const int e = h ? eAll : mid;
    int i = s;
    // 2-edge unroll: 8 f16x8 temps (32 VGPR) -> no spill at 128-VGPR budget
    for (; i + 1 < e; i += 2) {
      const int c0 = col[i], c1 = col[i + 1];
      const f16* p0 = xh + (size_t)c0 * HIDDEN + g * 8;
      const f16* p1 = xh + (size_t)c1 * HIDDEN + g * 8;
      f16x8 u0 = *(const f16x8*)(p0);
      f16x8 u1 = *(const f16x8*)(p0 + 32);
      f16x8 u2 = *(const f16x8*)(p0 + 64);
      f16x8 u3 = *(const f16x8*)(p0 + 96);
      f16x8 v0 = *(const f16x8*)(p1);
      f16x8 v1 = *(const f16x8*)(p1 + 32);
      f16x8 v2 = *(const f16x8*)(p1 + 64);
      f16x8 v3 = *(const f16x8*)(p1 + 96);
#pragma unroll
      for (int j = 0; j < 8; ++j) {
        a32[0][j] += (float)u0[j] + (float)v0[j];
        a32[1][j] += (float)u1[j] + (float)v1[j];
        a32[2][j] += (float)u2[j] + (float)v2[j];
        a32[3][j] += (float)u3[j] + (float)v3[j];
      }
    }
    if (i < e) {
      const int c0 = col[i];
      const f16* p0 = xh + (size_t)c0 * HIDDEN + g * 8;
      f16x8 u0 = *(const f16x8*)(p0);
      f16x8 u1 = *(const f16x8*)(p0 + 32);
      f16x8 u2 = *(const f16x8*)(p0 + 64);
      f16x8 u3 = *(const f16x8*)(p0 + 96);
#pragma unroll
      for (int j = 0; j < 8; ++j) {
        a32[0][j] += (float)u0[j];
        a32[1][j] += (float)u1[j];
        a32[2][j] += (float)u2[j];
        a32[3][j] += (float)u3[j];
      }
    }
  }

  // ---- symmetric combine: each wave writes its partial, ONE barrier, each
  // reads the other's and adds (commutative -> bit-identical in both waves)
  {
    float (*mine)[132] = h ? bufB : bufA;
#pragma unroll
    for (int ks = 0; ks < 4; ++ks) {
      *(float4*)&mine[r][ks * 32 + g * 8] =
          make_float4(a32[ks][0], a32[ks][1], a32[ks][2], a32[ks][3]);
      *(float4*)&mine[r][ks * 32 + g * 8 + 4] =
          make_float4(a32[ks][4], a32[ks][5], a32[ks][6], a32[ks][7]);
    }
  }
  __syncthreads();
  {
    float (*other)[132] = h ? bufA : bufB;
#pragma unroll
    for (int ks = 0; ks < 4; ++ks) {
      float4 q0 = *(const float4*)&other[r][ks * 32 + g * 8];
      float4 q1 = *(const float4*)&other[r][ks * 32 + g * 8 + 4];
      a32[ks][0] += q0.x; a32[ks][1] += q0.y; a32[ks][2] += q0.z; a32[ks][3] += q0.w;
      a32[ks][4] += q1.x; a32[ks][5] += q1.y; a32[ks][6] += q1.z; a32[ks][7] += q1.w;
    }
  }
  __syncthreads();   // combine reads done; bufA free for h1

  f32x4 acc[4];      // this wave's 4 nf fragments: nf = h*4 + nfi
#pragma unroll
  for (int i = 0; i < 4; ++i) acc[i] = (f32x4){0.f, 0.f, 0.f, 0.f};

  // ---- GEMM1: acc[nfi] += a32(16x128) @ W1[:, (h*4+nfi)*16..]
#pragma unroll
  for (int ks = 0; ks < 4; ++ks) {
    short8 ah, al;
#pragma unroll
    for (int j = 0; j < 8; ++j) {
      ushort hh = f2bf(a32[ks][j]);
      ah[j] = (short)hh;
      al[j] = (short)f2bf(a32[ks][j] - bf2f(hh));
    }
#pragma unroll
    for (int nfi = 0; nfi < 4; ++nfi) {
      const ushort* bp = W1p + ((size_t)(ks * 8 + h * 4 + nfi) * 64 + lane) * 8;
      short8 bh = *(const short8*)bp;
      short8 bl = *(const short8*)(bp + 16384);
      acc[nfi] = __builtin_amdgcn_mfma_f32_16x16x32_bf16(ah, bh, acc[nfi], 0, 0, 0);
      acc[nfi] = __builtin_amdgcn_mfma_f32_16x16x32_bf16(al, bh, acc[nfi], 0, 0, 0);
      acc[nfi] = __builtin_amdgcn_mfma_f32_16x16x32_bf16(ah, bl, acc[nfi], 0, 0, 0);
    }
  }

  // ---- bias + relu -> h1 (cols [64h, 64h+64)) in bufA
#pragma unroll
  for (int nfi = 0; nfi < 4; ++nfi) {
    const int nf = h * 4 + nfi;
    float bv = b1[nf * 16 + r];
#pragma unroll
    for (int q = 0; q < 4; ++q)
      bufA[g * 4 + q][nf * 16 + r] = fmaxf(acc[nfi][q] + bv, 0.f);
    acc[nfi] = (f32x4){0.f, 0.f, 0.f, 0.f};
  }
  __syncthreads();   // full h1 visible

  // ---- GEMM2: acc[nfi] += h1(16x128) @ W2[:, (h*4+nfi)*16..]
#pragma unroll
  for (int ks = 0; ks < 4; ++ks) {
    const float* hp = &bufA[r][ks * 32 + g * 8];
    float4 a0 = *(const float4*)hp;
    float4 a1 = *(const float4*)(hp + 4);
    float av[8] = {a0.x, a0.y, a0.z, a0.w, a1.x, a1.y, a1.z, a1.w};
    short8 ah, al;
#pragma unroll
    for (int j = 0; j < 8; ++j) {
      ushort hh = f2bf(av[j]);
      ah[j] = (short)hh;
      al[j] = (short)f2bf(av[j] - bf2f(hh));
    }
#pragma unroll
    for (int nfi = 0; nfi < 4; ++nfi) {
      const ushort* bp = W2p + ((size_t)(ks * 8 + h * 4 + nfi) * 64 + lane) * 8;
      short8 bh = *(const short8*)bp;
      short8 bl = *(const short8*)(bp + 16384);
      acc[nfi] = __builtin_amdgcn_mfma_f32_16x16x32_bf16(ah, bh, acc[nfi], 0, 0, 0);
      acc[nfi] = __builtin_amdgcn_mfma_f32_16x16x32_bf16(al, bh, acc[nfi], 0, 0, 0);
      acc[nfi] = __builtin_amdgcn_mfma_f32_16x16x32_bf16(ah, bl, acc[nfi], 0, 0, 0);
    }
  }

  if (!doReadout) {
    // h2 -> bufB (bufA may still be read by other wave's GEMM2; disjoint)
#pragma unroll
    for (int nfi = 0; nfi < 4; ++nfi) {
      const int nf = h * 4 + nfi;
      float bv = b2[nf * 16 + r];
#pragma unroll
      for (int q = 0; q < 4; ++q)
        bufB[g * 4 + q][nf * 16 + r] = fmaxf(acc[nfi][q] + bv, 0.f);
    }
    __syncthreads();
    // coalesced fp16 stores: 128 threads cover 16 rows x 128 cols
    const int rr = t >> 3;             // 0..15
    const int gm = mBase + rr;
    if (gm < M) {
#pragma unroll
      for (int i = 0; i < 2; ++i) {
        const int c0 = (t & 7) * 8 + i * 64;   // contiguous 128B per 8 threads
        float4 v0 = *(const float4*)&bufB[rr][c0];
        float4 v1 = *(const float4*)&bufB[rr][c0 + 4];
        f16x8 o;
        o[0] = (f16)v0.x; o[1] = (f16)v0.y; o[2] = (f16)v0.z; o[3] = (f16)v0.w;
        o[4] = (f16)v1.x; o[5] = (f16)v1.y; o[6] = (f16)v1.z; o[7] = (f16)v1.w;
        *(f16x8*)(Ch + (size_t)gm * HIDDEN + c0) = o;
      }
    }
  } else {
    // readout: each wave dots its 64 cols, reduce over r-lanes, then
    // cross-wave combine via pr[16].
    float p[4] = {0.f, 0.f, 0.f, 0.f};
#pragma unroll
    for (int nfi = 0; nfi < 4; ++nfi) {
      const int nf = h * 4 + nfi;
      float bv = b2[nf * 16 + r];
      float wv = Wr[nf * 16 + r];
#pragma unroll
      for (int q = 0; q < 4; ++q) {
        float hv = fmaxf(acc[nfi][q] + bv, 0.f);
        p[q] += hv * wv;
      }
    }
#pragma unroll
    for (int q = 0; q < 4; ++q) {
      p[q] += __shfl_xor(p[q], 8);
      p[q] += __shfl_xor(p[q], 4);
      p[q] += __shfl_xor(p[q], 2);
      p[q] += __shfl_xor(p[q], 1);
    }
    if (h == 1 && r == 0) {
#pragma unroll
      for (int q = 0; q < 4; ++q) pr[g * 4 + q] = p[q];
    }
    __syncthreads();
    if (h == 0 && r == 0) {
      float brv = br[0];
#pragma unroll
      for (int q = 0; q < 4; ++q) {
        int gm = mBase + g * 4 + q;
        if (gm < M) outv[gm] = p[q] + pr[g * 4 + q] + brv;
      }
    }
  }
}

extern "C" void kernel_launch(void* const* d_in, const int* in_sizes, int n_in,
                              void* d_out, int out_size, void* d_ws,
                              size_t ws_size, hipStream_t stream) {
  const float* x = (const float*)d_in[0];
  const int* ei = (const int*)d_in[1];
  const float* W1_0 = (const float*)d_in[2];
  const float* b1_0 = (const float*)d_in[3];
  const float* W2_0 = (const float*)d_in[4];
  const float* b2_0 = (const float*)d_in[5];
  const float* W1_1 = (const float*)d_in[6];
  const float* b1_1 = (const float*)d_in[7];
  const float* W2_1 = (const float*)d_in[8];
  const float* b2_1 = (const float*)d_in[9];
  const float* Wr = (const float*)d_in[10];
  const float* br = (const float*)d_in[11];

  const int M = in_sizes[0] / HIDDEN;  // 50000 nodes
  const int E = in_sizes[1] / 2;       // 800000 edges
  const int* src = ei;
  const int* dst = ei + E;
  const int NB = (M + NPB - 1) >> NB_SHIFT;  // 391 buckets

  // workspace layout. pairs dies after build_csr; scratch region reused.
  int* pairs = (int*)d_ws;                   // [E] packed (dst&127)<<25|src
  f16* xh = (f16*)(pairs + E);               // [M,128] fp16 features
  f16* Bh = xh + (size_t)M * HIDDEN;         // [M,128] fp16 layer-0 hidden
  int* rowptr = (int*)(Bh + (size_t)M * HIDDEN); // [M+1]
  int* col = rowptr + M + 1;                 // [E]
  int* bcnt = col + E;                       // [512]
  int* pairOff = bcnt + 512;                 // [513]
  int* gCursor = pairOff + 513;              // [512]
  ushort* Wpk = (ushort*)(gCursor + 512);    // 4 x (hi 32KB + lo 32KB)

  const int ginBlocks = (M + 15) / 16;       // 1 block = 2 waves = 16 nodes
  const int cvtBlocks = (M * 16 + 255) / 256;  // M*128/8 threads
  const int edgeBlocks = (E + EPB - 1) / EPB;
  float* out = (float*)d_out;

  // ---- prep: prepack weights + fp16 feature copy + bcnt zero (1 dispatch)
  prep_kernel<<<32 + cvtBlocks, 256, 0, stream>>>(
      W1_0, W2_0, W1_1, W2_1, Wpk, x, xh, M * 16, bcnt);

  // ---- build CSR via bucket sort
  bucket_hist_kernel<<<edgeBlocks, 256, 0, stream>>>(dst, bcnt, E, NB);
  scan_buckets_kernel<<<1, 256, 0, stream>>>(bcnt, pairOff, gCursor, NB);
  partition_kernel<<<edgeBlocks, 256, 0, stream>>>(src, dst, gCursor, pairs,
                                                   E, NB);
  build_csr_kernel<<<NB, 256, 0, stream>>>(pairs, pairOff, rowptr, col, M, E,
                                           NB);

  // ---- layer 0: fused gather+MLP (xh -> Bh fp16)
  gin_layer_kernel<<<ginBlocks, 128, 0, stream>>>(
      xh, rowptr, col, Wpk, b1_0, Wpk + 32768, b2_0, Bh,
      nullptr, nullptr, nullptr, M, 0);

  // ---- layer 1: fused gather+MLP+readout (Bh -> out)
  gin_layer_kernel<<<ginBlocks, 128, 0, stream>>>(
      Bh, rowptr, col, Wpk + 65536, b1_1, Wpk + 98304, b2_1, nullptr,
      Wr, br, out, M, 1);
}

// Round 14
// 226.556 us; speedup vs baseline: 1.0672x; 1.0577x over previous
//
#include <hip/hip_runtime.h>

#define HIDDEN 128
#define NB_SHIFT 7            // 128 dst nodes per bucket
#define NPB 128               // nodes per bucket
#define EPB 4096              // edges per partition/hist block

typedef __attribute__((ext_vector_type(8))) short short8;
typedef __attribute__((ext_vector_type(4))) float f32x4;
typedef _Float16 f16;
typedef __attribute__((ext_vector_type(8))) _Float16 f16x8;

// float -> bf16 (RNE), and back
__device__ __forceinline__ ushort f2bf(float a) {
  union { float f; unsigned u; } c; c.f = a;
  return (ushort)((c.u + 0x7FFFu + ((c.u >> 16) & 1u)) >> 16);
}
__device__ __forceinline__ float bf2f(ushort h) {
  union { unsigned u; float f; } c; c.u = ((unsigned)h) << 16;
  return c.f;
}

// ---------------------------------------------------------------------------
// PREP kernel: prepack weights (blocks 0..31, block 0 also zeroes bcnt) +
// fp32->fp16 feature convert (blocks 32..). Merges 3 dispatches into 1.
// Prepack fragment mapping (must match mlp A-side):
//   frag (ks, nf), lane, j -> k = ks*32 + (lane>>4)*8 + j, n = nf*16 + (lane&15)
// ---------------------------------------------------------------------------
__global__ __launch_bounds__(256) void prep_kernel(
    const float* __restrict__ Wa, const float* __restrict__ Wb,
    const float* __restrict__ Wc, const float* __restrict__ Wd,
    ushort* __restrict__ wout, const float* __restrict__ xin,
    f16* __restrict__ xh, int n8, int* __restrict__ bcnt) {
  const int t = threadIdx.x;
  if (blockIdx.x < 32) {
    if (blockIdx.x == 0) { bcnt[t] = 0; bcnt[t + 256] = 0; }
    int idx = blockIdx.x * 256 + t;  // 0..8191
    int w = idx >> 11;
    int rem = idx & 2047;
    int ks = rem >> 9;
    int nf = (rem >> 6) & 7;
    int lane = rem & 63;
    const float* W = (w == 0) ? Wa : (w == 1) ? Wb : (w == 2) ? Wc : Wd;
    const int kbase = ks * 32 + (lane >> 4) * 8;
    const int n = nf * 16 + (lane & 15);
    ushort* oh = wout + (size_t)w * 32768 + (size_t)rem * 8;
    ushort* ol = oh + 16384;
#pragma unroll
    for (int j = 0; j < 8; ++j) {
      float v = W[(size_t)(kbase + j) * HIDDEN + n];
      ushort h = f2bf(v);
      oh[j] = h;
      ol[j] = f2bf(v - bf2f(h));
    }
  } else {
    int i = (blockIdx.x - 32) * 256 + t;
    if (i >= n8) return;
    const float4* p = (const float4*)(xin + (size_t)i * 8);
    float4 a = p[0], b = p[1];
    f16x8 o;
    o[0] = (f16)a.x; o[1] = (f16)a.y; o[2] = (f16)a.z; o[3] = (f16)a.w;
    o[4] = (f16)b.x; o[5] = (f16)b.y; o[6] = (f16)b.z; o[7] = (f16)b.w;
    *(f16x8*)(xh + (size_t)i * 8) = o;
  }
}

// ---------------------------------------------------------------------------
// CSR build A: per-bucket edge histogram (LDS-local, then merge).
// ---------------------------------------------------------------------------
__global__ __launch_bounds__(256) void bucket_hist_kernel(
    const int* __restrict__ dst, int* __restrict__ bcnt, int E, int NB) {
  __shared__ int loc[512];
  const int t = threadIdx.x;
  loc[t] = 0; loc[t + 256] = 0;
  __syncthreads();
  const int base = blockIdx.x * EPB;
  const int end = min(base + EPB, E);
  for (int e = base + t; e < end; e += 256)
    atomicAdd(&loc[dst[e] >> NB_SHIFT], 1);
  __syncthreads();
  for (int b = t; b < NB; b += 256)
    if (loc[b]) atomicAdd(&bcnt[b], loc[b]);
}

// ---------------------------------------------------------------------------
// CSR build B: exclusive scan of <=512 bucket counts -> pairOff + gCursor.
// ---------------------------------------------------------------------------
__global__ __launch_bounds__(256) void scan_buckets_kernel(
    const int* __restrict__ bcnt, int* __restrict__ pairOff,
    int* __restrict__ gCursor, int NB) {
  __shared__ int sh[512];
  const int t = threadIdx.x;
  const int v0 = (t < NB) ? bcnt[t] : 0;
  const int v1 = (t + 256 < NB) ? bcnt[t + 256] : 0;
  sh[t] = v0; sh[t + 256] = v1;
  __syncthreads();
#pragma unroll
  for (int off = 1; off < 512; off <<= 1) {
    int a = (t >= off) ? sh[t - off] : 0;
    int b = (t + 256 >= off) ? sh[t + 256 - off] : 0;
    __syncthreads();
    sh[t] += a; sh[t + 256] += b;
    __syncthreads();
  }
  const int e0 = sh[t] - v0;        // exclusive
  const int e1 = sh[t + 256] - v1;
  pairOff[t] = e0; gCursor[t] = e0;
  pairOff[t + 256] = e1; gCursor[t + 256] = e1;
  if (t == 255) pairOff[512] = sh[511];
}

// ---------------------------------------------------------------------------
// CSR build C: partition edges into bucket-contiguous PACKED pairs:
//   p = (dst & 127) << 25 | src      (src < 2^25)
// ---------------------------------------------------------------------------
__global__ __launch_bounds__(256) void partition_kernel(
    const int* __restrict__ src, const int* __restrict__ dst,
    int* __restrict__ gCursor, int* __restrict__ pairs, int E, int NB) {
  __shared__ int loc[512];
  __shared__ int cur[512];
  const int t = threadIdx.x;
  loc[t] = 0; loc[t + 256] = 0;
  __syncthreads();
  const int base = blockIdx.x * EPB;
  const int end = min(base + EPB, E);
  for (int e = base + t; e < end; e += 256)
    atomicAdd(&loc[dst[e] >> NB_SHIFT], 1);
  __syncthreads();
  for (int b = t; b < NB; b += 256)
    cur[b] = loc[b] ? atomicAdd(&gCursor[b], loc[b]) : 0;
  __syncthreads();
  for (int e = base + t; e < end; e += 256) {
    const int d = dst[e];
    const int p = atomicAdd(&cur[d >> NB_SHIFT], 1);
    pairs[p] = ((d & (NPB - 1)) << 25) | src[e];
  }
}

// ---------------------------------------------------------------------------
// CSR build D: one block per bucket -> rowptr + col (dense, L2-resident).
// ---------------------------------------------------------------------------
__global__ __launch_bounds__(256) void build_csr_kernel(
    const int* __restrict__ pairs, const int* __restrict__ pairOff,
    int* __restrict__ rowptr, int* __restrict__ col, int M, int E, int NB) {
  __shared__ int deg[NPB];
  __shared__ int pre[NPB];
  __shared__ int cur[NPB];
  const int b = blockIdx.x;
  const int t = threadIdx.x;
  const int s = pairOff[b];
  const int e2 = pairOff[b + 1];
  const int nodeBase = b << NB_SHIFT;
  const int nNodes = min(NPB, M - nodeBase);
  if (t < NPB) deg[t] = 0;
  __syncthreads();
  for (int i = s + t; i < e2; i += 256)
    atomicAdd(&deg[((unsigned)pairs[i]) >> 25], 1);
  __syncthreads();
  if (t < NPB) pre[t] = deg[t];
  __syncthreads();
#pragma unroll
  for (int off = 1; off < NPB; off <<= 1) {
    int v = (t < NPB && t >= off) ? pre[t - off] : 0;
    __syncthreads();
    if (t < NPB) pre[t] += v;
    __syncthreads();
  }
  if (t < nNodes) rowptr[nodeBase + t] = s + pre[t] - deg[t];
  if (b == NB - 1 && t == 0) rowptr[M] = E;
  if (t < NPB) cur[t] = pre[t] - deg[t];
  __syncthreads();
  for (int i = s + t; i < e2; i += 256) {
    const int pr = pairs[i];
    const int pos = s + atomicAdd(&cur[((unsigned)pr) >> 25], 1);
    col[pos] = pr & 0x1FFFFFF;
  }
}

// ---------------------------------------------------------------------------
// FUSED GIN layer, EDGE-SPLIT wave pairs — EXACT R11 structure (best: 234.0
// µs, gin 53 µs, VGPR 56, no spill). R12 (4-way split) and R13 (symmetric
// combine) both regressed; the 4-phase alternating combine is NOT the
// bottleneck. Block = 128 threads = 2 waves per 16-node group; wave h
// gathers edge half [s,mid)/[mid,e) of the SAME 16 nodes (6250 waves, the
// concurrency win over R5's 3125). fp32 partials combine via ONE 8.4 KB LDS
// buffer (w1 write -> w0 add -> w0 write full -> w1 read); MLP splits nf
// 0-3 / 4-7 per wave. launch_bounds(128,4) = 128-VGPR budget (R10 spill
// lesson). LDS 8.7 KB.
// ---------------------------------------------------------------------------
__global__ __launch_bounds__(128, 4) void gin_layer_kernel(
    const f16* __restrict__ xh, const int* __restrict__ rowptr,
    const int* __restrict__ col, const ushort* __restrict__ W1p,
    const float* __restrict__ b1, const ushort* __restrict__ W2p,
    const float* __restrict__ b2, f16* __restrict__ Ch,
    const float* __restrict__ Wr, const float* __restrict__ br,
    float* __restrict__ outv, int M, int doReadout) {
  __shared__ float buf[16][132];
  __shared__ float pr[16];
  const int t = threadIdx.x;
  const int lane = t & 63;
  const int h = t >> 6;        // wave half: 0 or 1
  const int r = lane & 15;     // node row within group / D col index
  const int g = lane >> 4;     // k-group / D row group
  const int mBase = blockIdx.x * 16;
  int arow = mBase + r;
  if (arow > M - 1) arow = M - 1;  // clamp: garbage only affects rows >= M

  // ---- gather partial over this wave's edge half (+ self term on wave 0)
  float a32[4][8];
  if (h == 0) {
    const f16* rp = xh + (size_t)arow * HIDDEN + g * 8;
    f16x8 s0 = *(const f16x8*)(rp);
    f16x8 s1 = *(const f16x8*)(rp + 32);
    f16x8 s2 = *(const f16x8*)(rp + 64);
    f16x8 s3 = *(const f16x8*)(rp + 96);
#pragma unroll
    for (int j = 0; j < 8; ++j) {
      a32[0][j] = (float)s0[j]; a32[1][j] = (float)s1[j];
      a32[2][j] = (float)s2[j]; a32[3][j] = (float)s3[j];
    }
  } else {
#pragma unroll
    for (int ks = 0; ks < 4; ++ks)
#pragma unroll
      for (int j = 0; j < 8; ++j) a32[ks][j] = 0.f;
  }
  {
    const int sAll = rowptr[arow];
    const int eAll = rowptr[arow + 1];
    const int mid = sAll + ((eAll - sAll) >> 1);
    const int s = h ? mid : sAll;
    const int e = h ? eAll : mid;
    int i = s;
    // 2-edge unroll: 8 f16x8 temps (32 VGPR) -> no spill at 128-VGPR budget
    for (; i + 1 < e; i += 2) {
      const int c0 = col[i], c1 = col[i + 1];
      const f16* p0 = xh + (size_t)c0 * HIDDEN + g * 8;
      const f16* p1 = xh + (size_t)c1 * HIDDEN + g * 8;
      f16x8 u0 = *(const f16x8*)(p0);
      f16x8 u1 = *(const f16x8*)(p0 + 32);
      f16x8 u2 = *(const f16x8*)(p0 + 64);
      f16x8 u3 = *(const f16x8*)(p0 + 96);
      f16x8 v0 = *(const f16x8*)(p1);
      f16x8 v1 = *(const f16x8*)(p1 + 32);
      f16x8 v2 = *(const f16x8*)(p1 + 64);
      f16x8 v3 = *(const f16x8*)(p1 + 96);
#pragma unroll
      for (int j = 0; j < 8; ++j) {
        a32[0][j] += (float)u0[j] + (float)v0[j];
        a32[1][j] += (float)u1[j] + (float)v1[j];
        a32[2][j] += (float)u2[j] + (float)v2[j];
        a32[3][j] += (float)u3[j] + (float)v3[j];
      }
    }
    if (i < e) {
      const int c0 = col[i];
      const f16* p0 = xh + (size_t)c0 * HIDDEN + g * 8;
      f16x8 u0 = *(const f16x8*)(p0);
      f16x8 u1 = *(const f16x8*)(p0 + 32);
      f16x8 u2 = *(const f16x8*)(p0 + 64);
      f16x8 u3 = *(const f16x8*)(p0 + 96);
#pragma unroll
      for (int j = 0; j < 8; ++j) {
        a32[0][j] += (float)u0[j];
        a32[1][j] += (float)u1[j];
        a32[2][j] += (float)u2[j];
        a32[3][j] += (float)u3[j];
      }
    }
  }

  // ---- combine partials: w1 -> LDS; w0 adds, writes full; w1 reads full
  if (h == 1) {
#pragma unroll
    for (int ks = 0; ks < 4; ++ks) {
      *(float4*)&buf[r][ks * 32 + g * 8] =
          make_float4(a32[ks][0], a32[ks][1], a32[ks][2], a32[ks][3]);
      *(float4*)&buf[r][ks * 32 + g * 8 + 4] =
          make_float4(a32[ks][4], a32[ks][5], a32[ks][6], a32[ks][7]);
    }
  }
  __syncthreads();
  if (h == 0) {
#pragma unroll
    for (int ks = 0; ks < 4; ++ks) {
      float4 q0 = *(const float4*)&buf[r][ks * 32 + g * 8];
      float4 q1 = *(const float4*)&buf[r][ks * 32 + g * 8 + 4];
      a32[ks][0] += q0.x; a32[ks][1] += q0.y; a32[ks][2] += q0.z; a32[ks][3] += q0.w;
      a32[ks][4] += q1.x; a32[ks][5] += q1.y; a32[ks][6] += q1.z; a32[ks][7] += q1.w;
    }
  }
  __syncthreads();
  if (h == 0) {
#pragma unroll
    for (int ks = 0; ks < 4; ++ks) {
      *(float4*)&buf[r][ks * 32 + g * 8] =
          make_float4(a32[ks][0], a32[ks][1], a32[ks][2], a32[ks][3]);
      *(float4*)&buf[r][ks * 32 + g * 8 + 4] =
          make_float4(a32[ks][4], a32[ks][5], a32[ks][6], a32[ks][7]);
    }
  }
  __syncthreads();
  if (h == 1) {
#pragma unroll
    for (int ks = 0; ks < 4; ++ks) {
      float4 q0 = *(const float4*)&buf[r][ks * 32 + g * 8];
      float4 q1 = *(const float4*)&buf[r][ks * 32 + g * 8 + 4];
      a32[ks][0] = q0.x; a32[ks][1] = q0.y; a32[ks][2] = q0.z; a32[ks][3] = q0.w;
      a32[ks][4] = q1.x; a32[ks][5] = q1.y; a32[ks][6] = q1.z; a32[ks][7] = q1.w;
    }
  }
  __syncthreads();   // buf reads done before h1 overwrites

  f32x4 acc[4];      // this wave's 4 nf fragments: nf = h*4 + nfi
#pragma unroll
  for (int i = 0; i < 4; ++i) acc[i] = (f32x4){0.f, 0.f, 0.f, 0.f};

  // ---- GEMM1: acc[nfi] += a32(16x128) @ W1[:, (h*4+nfi)*16..]
#pragma unroll
  for (int ks = 0; ks < 4; ++ks) {
    short8 ah, al;
#pragma unroll
    for (int j = 0; j < 8; ++j) {
      ushort hh = f2bf(a32[ks][j]);
      ah[j] = (short)hh;
      al[j] = (short)f2bf(a32[ks][j] - bf2f(hh));
    }
#pragma unroll
    for (int nfi = 0; nfi < 4; ++nfi) {
      const ushort* bp = W1p + ((size_t)(ks * 8 + h * 4 + nfi) * 64 + lane) * 8;
      short8 bh = *(const short8*)bp;
      short8 bl = *(const short8*)(bp + 16384);
      acc[nfi] = __builtin_amdgcn_mfma_f32_16x16x32_bf16(ah, bh, acc[nfi], 0, 0, 0);
      acc[nfi] = __builtin_amdgcn_mfma_f32_16x16x32_bf16(al, bh, acc[nfi], 0, 0, 0);
      acc[nfi] = __builtin_amdgcn_mfma_f32_16x16x32_bf16(ah, bl, acc[nfi], 0, 0, 0);
    }
  }

  // ---- bias + relu -> h1 (cols [64h, 64h+64)) in buf
#pragma unroll
  for (int nfi = 0; nfi < 4; ++nfi) {
    const int nf = h * 4 + nfi;
    float bv = b1[nf * 16 + r];
#pragma unroll
    for (int q = 0; q < 4; ++q)
      buf[g * 4 + q][nf * 16 + r] = fmaxf(acc[nfi][q] + bv, 0.f);
    acc[nfi] = (f32x4){0.f, 0.f, 0.f, 0.f};
  }
  __syncthreads();   // full h1 visible

  // ---- GEMM2: acc[nfi] += h1(16x128) @ W2[:, (h*4+nfi)*16..]
#pragma unroll
  for (int ks = 0; ks < 4; ++ks) {
    const float* hp = &buf[r][ks * 32 + g * 8];
    float4 a0 = *(const float4*)hp;
    float4 a1 = *(const float4*)(hp + 4);
    float av[8] = {a0.x, a0.y, a0.z, a0.w, a1.x, a1.y, a1.z, a1.w};
    short8 ah, al;
#pragma unroll
    for (int j = 0; j < 8; ++j) {
      ushort hh = f2bf(av[j]);
      ah[j] = (short)hh;
      al[j] = (short)f2bf(av[j] - bf2f(hh));
    }
#pragma unroll
    for (int nfi = 0; nfi < 4; ++nfi) {
      const ushort* bp = W2p + ((size_t)(ks * 8 + h * 4 + nfi) * 64 + lane) * 8;
      short8 bh = *(const short8*)bp;
      short8 bl = *(const short8*)(bp + 16384);
      acc[nfi] = __builtin_amdgcn_mfma_f32_16x16x32_bf16(ah, bh, acc[nfi], 0, 0, 0);
      acc[nfi] = __builtin_amdgcn_mfma_f32_16x16x32_bf16(al, bh, acc[nfi], 0, 0, 0);
      acc[nfi] = __builtin_amdgcn_mfma_f32_16x16x32_bf16(ah, bl, acc[nfi], 0, 0, 0);
    }
  }

  if (!doReadout) {
    __syncthreads();  // GEMM2 h1 reads done before h2 overwrite
#pragma unroll
    for (int nfi = 0; nfi < 4; ++nfi) {
      const int nf = h * 4 + nfi;
      float bv = b2[nf * 16 + r];
#pragma unroll
      for (int q = 0; q < 4; ++q)
        buf[g * 4 + q][nf * 16 + r] = fmaxf(acc[nfi][q] + bv, 0.f);
    }
    __syncthreads();
    // coalesced fp16 stores: 128 threads cover 16 rows x 128 cols
    const int rr = t >> 3;             // 0..15
    const int gm = mBase + rr;
    if (gm < M) {
#pragma unroll
      for (int i = 0; i < 2; ++i) {
        const int c0 = (t & 7) * 8 + i * 64;   // contiguous 128B per 8 threads
        float4 v0 = *(const float4*)&buf[rr][c0];
        float4 v1 = *(const float4*)&buf[rr][c0 + 4];
        f16x8 o;
        o[0] = (f16)v0.x; o[1] = (f16)v0.y; o[2] = (f16)v0.z; o[3] = (f16)v0.w;
        o[4] = (f16)v1.x; o[5] = (f16)v1.y; o[6] = (f16)v1.z; o[7] = (f16)v1.w;
        *(f16x8*)(Ch + (size_t)gm * HIDDEN + c0) = o;
      }
    }
  } else {
    // readout: each wave dots its 64 cols, reduce over r-lanes, then
    // cross-wave combine via pr[16].
    float p[4] = {0.f, 0.f, 0.f, 0.f};
#pragma unroll
    for (int nfi = 0; nfi < 4; ++nfi) {
      const int nf = h * 4 + nfi;
      float bv = b2[nf * 16 + r];
      float wv = Wr[nf * 16 + r];
#pragma unroll
      for (int q = 0; q < 4; ++q) {
        float hv = fmaxf(acc[nfi][q] + bv, 0.f);
        p[q] += hv * wv;
      }
    }
#pragma unroll
    for (int q = 0; q < 4; ++q) {
      p[q] += __shfl_xor(p[q], 8);
      p[q] += __shfl_xor(p[q], 4);
      p[q] += __shfl_xor(p[q], 2);
      p[q] += __shfl_xor(p[q], 1);
    }
    if (h == 1 && r == 0) {
#pragma unroll
      for (int q = 0; q < 4; ++q) pr[g * 4 + q] = p[q];
    }
    __syncthreads();
    if (h == 0 && r == 0) {
      float brv = br[0];
#pragma unroll
      for (int q = 0; q < 4; ++q) {
        int gm = mBase + g * 4 + q;
        if (gm < M) outv[gm] = p[q] + pr[g * 4 + q] + brv;
      }
    }
  }
}

extern "C" void kernel_launch(void* const* d_in, const int* in_sizes, int n_in,
                              void* d_out, int out_size, void* d_ws,
                              size_t ws_size, hipStream_t stream) {
  const float* x = (const float*)d_in[0];
  const int* ei = (const int*)d_in[1];
  const float* W1_0 = (const float*)d_in[2];
  const float* b1_0 = (const float*)d_in[3];
  const float* W2_0 = (const float*)d_in[4];
  const float* b2_0 = (const float*)d_in[5];
  const float* W1_1 = (const float*)d_in[6];
  const float* b1_1 = (const float*)d_in[7];
  const float* W2_1 = (const float*)d_in[8];
  const float* b2_1 = (const float*)d_in[9];
  const float* Wr = (const float*)d_in[10];
  const float* br = (const float*)d_in[11];

  const int M = in_sizes[0] / HIDDEN;  // 50000 nodes
  const int E = in_sizes[1] / 2;       // 800000 edges
  const int* src = ei;
  const int* dst = ei + E;
  const int NB = (M + NPB - 1) >> NB_SHIFT;  // 391 buckets

  // workspace layout. pairs dies after build_csr; scratch region reused.
  int* pairs = (int*)d_ws;                   // [E] packed (dst&127)<<25|src
  f16* xh = (f16*)(pairs + E);               // [M,128] fp16 features
  f16* Bh = xh + (size_t)M * HIDDEN;         // [M,128] fp16 layer-0 hidden
  int* rowptr = (int*)(Bh + (size_t)M * HIDDEN); // [M+1]
  int* col = rowptr + M + 1;                 // [E]
  int* bcnt = col + E;                       // [512]
  int* pairOff = bcnt + 512;                 // [513]
  int* gCursor = pairOff + 513;              // [512]
  ushort* Wpk = (ushort*)(gCursor + 512);    // 4 x (hi 32KB + lo 32KB)

  const int ginBlocks = (M + 15) / 16;       // 1 block = 2 waves = 16 nodes
  const int cvtBlocks = (M * 16 + 255) / 256;  // M*128/8 threads
  const int edgeBlocks = (E + EPB - 1) / EPB;
  float* out = (float*)d_out;

  // ---- prep: prepack weights + fp16 feature copy + bcnt zero (1 dispatch)
  prep_kernel<<<32 + cvtBlocks, 256, 0, stream>>>(
      W1_0, W2_0, W1_1, W2_1, Wpk, x, xh, M * 16, bcnt);

  // ---- build CSR via bucket sort
  bucket_hist_kernel<<<edgeBlocks, 256, 0, stream>>>(dst, bcnt, E, NB);
  scan_buckets_kernel<<<1, 256, 0, stream>>>(bcnt, pairOff, gCursor, NB);
  partition_kernel<<<edgeBlocks, 256, 0, stream>>>(src, dst, gCursor, pairs,
                                                   E, NB);
  build_csr_kernel<<<NB, 256, 0, stream>>>(pairs, pairOff, rowptr, col, M, E,
                                           NB);

  // ---- layer 0: fused gather+MLP (xh -> Bh fp16)
  gin_layer_kernel<<<ginBlocks, 128, 0, stream>>>(
      xh, rowptr, col, Wpk, b1_0, Wpk + 32768, b2_0, Bh,
      nullptr, nullptr, nullptr, M, 0);

  // ---- layer 1: fused gather+MLP+readout (Bh -> out)
  gin_layer_kernel<<<ginBlocks, 128, 0, stream>>>(
      Bh, rowptr, col, Wpk + 65536, b1_1, Wpk + 98304, b2_1, nullptr,
      Wr, br, out, M, 1);
}